// Round 3
// baseline (1256.827 us; speedup 1.0000x reference)
//
#include <hip/hip_runtime.h>

#define N_A   50000
#define N_B   50000
#define NE    1600000
#define HID   128
#define DOUT  64

// ---------------------------------------------------------------------------
// CSR build: deg histogram -> 3-kernel exclusive scan -> fill (atomic cursor)
// ---------------------------------------------------------------------------
__global__ void count_deg(const int* __restrict__ dst, int* __restrict__ deg, int n) {
    int e = blockIdx.x * 256 + threadIdx.x;
    if (e < n) atomicAdd(&deg[dst[e]], 1);
}

__global__ void chunk_sum(const int* __restrict__ deg, int* __restrict__ bsum, int n) {
    __shared__ int s[256];
    int t = threadIdx.x;
    int i = blockIdx.x * 256 + t;
    s[t] = (i < n) ? deg[i] : 0;
    __syncthreads();
    for (int off = 128; off > 0; off >>= 1) {
        if (t < off) s[t] += s[t + off];
        __syncthreads();
    }
    if (t == 0) bsum[blockIdx.x] = s[0];
}

__global__ void scan_bsum(const int* __restrict__ bsum, int* __restrict__ boffs, int n) {
    // single block of 256; exclusive scan (n <= 256)
    __shared__ int s[256];
    int t = threadIdx.x;
    int v = (t < n) ? bsum[t] : 0;
    s[t] = v;
    __syncthreads();
    for (int off = 1; off < 256; off <<= 1) {
        int x = (t >= off) ? s[t - off] : 0;
        __syncthreads();
        s[t] += x;
        __syncthreads();
    }
    if (t < n) boffs[t] = s[t] - v;
}

__global__ void scan_chunks(const int* __restrict__ deg, const int* __restrict__ boffs,
                            int* __restrict__ indptr, int* __restrict__ cursor,
                            int n, int etot) {
    __shared__ int s[256];
    int t = threadIdx.x;
    int i = blockIdx.x * 256 + t;
    int v = (i < n) ? deg[i] : 0;
    s[t] = v;
    __syncthreads();
    for (int off = 1; off < 256; off <<= 1) {
        int x = (t >= off) ? s[t - off] : 0;
        __syncthreads();
        s[t] += x;
        __syncthreads();
    }
    int ip = boffs[blockIdx.x] + s[t] - v;
    if (i < n) { indptr[i] = ip; cursor[i] = ip; }
    if (i == n) indptr[i] = etot;
}

__global__ void fill_csr(const int* __restrict__ src, const int* __restrict__ dst,
                         int* __restrict__ cursor, int* __restrict__ col, int n) {
    int e = blockIdx.x * 256 + threadIdx.x;
    if (e < n) {
        int p = atomicAdd(&cursor[dst[e]], 1);
        col[p] = src[e];
    }
}

// ---------------------------------------------------------------------------
// Pull-based segment mean: one wave per dst node, 2 edges per VMEM instr.
// Lanes 0-31 handle edge i, lanes 32-63 edge i+1; each lane holds float4 of
// features (quad q = lane&31). Pair-reduce via __shfl_xor(...,32) at the end.
// ---------------------------------------------------------------------------
__global__ __launch_bounds__(256)
void agg_mean(const float* __restrict__ h, const int* __restrict__ indptr,
              const int* __restrict__ col, float* __restrict__ outm, int n) {
    int w = threadIdx.x >> 6;
    int l = threadIdx.x & 63;
    int v = blockIdx.x * 4 + w;
    if (v >= n) return;
    int s = indptr[v], e = indptr[v + 1];
    const int half = l >> 5;     // which edge of the pair this lane serves
    const int q    = l & 31;     // feature quad [0,32): 4 floats each
    const float4* h4 = (const float4*)h;
    float ax = 0.f, ay = 0.f, az = 0.f, aw = 0.f;
    int i = s;
    for (; i + 4 <= e; i += 4) {          // 4 edges per iteration, 2 loads in flight
        int u0 = col[i + half];
        int u1 = col[i + 2 + half];
        float4 x0 = h4[u0 * 32 + q];
        float4 x1 = h4[u1 * 32 + q];
        ax += x0.x + x1.x; ay += x0.y + x1.y;
        az += x0.z + x1.z; aw += x0.w + x1.w;
    }
    for (; i + 2 <= e; i += 2) {          // pair tail
        int u = col[i + half];
        float4 x = h4[u * 32 + q];
        ax += x.x; ay += x.y; az += x.z; aw += x.w;
    }
    if (i < e && half == 0) {             // odd last edge: low half only
        float4 x = h4[col[i] * 32 + q];
        ax += x.x; ay += x.y; az += x.z; aw += x.w;
    }
    // combine the two half-wave partial sums (feature quad q lives in lanes q and q+32)
    ax += __shfl_xor(ax, 32);
    ay += __shfl_xor(ay, 32);
    az += __shfl_xor(az, 32);
    aw += __shfl_xor(aw, 32);
    if (half == 0) {
        float inv = 1.0f / fmaxf((float)(e - s), 1.0f);
        float4 o;
        o.x = ax * inv; o.y = ay * inv; o.z = az * inv; o.w = aw * inv;
        ((float4*)outm)[v * 32 + q] = o;
    }
}

// ---------------------------------------------------------------------------
// Row-tiled fp32 GEMM: out[r][c] = act( A@W1 (+ B@W2) + bias )
// 256 threads, 64-row tile, 4 rows/thread, W staged in 64-col LDS chunks.
// Inner loop: 64 FMA per 8 ds_read_b128 (was 16 FMA per 4 LDS in v1).
// Asm stride 132: 4 p-groups land 2-way bank-aliased on b128 reads (free);
// stride 136 would be 4-way. LDS 65 KB/block -> 2 blocks/CU.
// Safe for out == A: each block reads only its own 64 rows (staged before
// epilogue) and writes only its own 64 rows.
// ---------------------------------------------------------------------------
#define AS 132   // Asm leading-dim stride (floats)

__device__ __forceinline__ void fma4(float4& a, float s, const float4& w) {
    a.x += s * w.x; a.y += s * w.y; a.z += s * w.z; a.w += s * w.w;
}

template <int COLS, bool TWO, bool RELU>
__global__ __launch_bounds__(256)
void gemm_rt(const float* __restrict__ A, const float* __restrict__ B,
             const float* __restrict__ W1, const float* __restrict__ W2,
             const float* __restrict__ bias, float* __restrict__ out, int nrows) {
    constexpr int NCH = COLS / 64;
    __shared__ float Asm[64 * AS];    // 64 rows x 128 feats (stride 132)
    __shared__ float Wsm[128 * 64];   // one 64-col chunk of W
    const int t = threadIdx.x;
    const int p = t >> 4, m = t & 15, m4 = m * 4;
    const int r0 = 4 * p;             // 4 consecutive rows per thread
    const int rbase = blockIdx.x * 64;

    float4 acc[NCH][4];
#pragma unroll
    for (int c = 0; c < NCH; ++c)
#pragma unroll
        for (int i = 0; i < 4; ++i)
            acc[c][i] = make_float4(0.f, 0.f, 0.f, 0.f);

#pragma unroll
    for (int sidx = 0; sidx < (TWO ? 2 : 1); ++sidx) {
        const float* Asrc = (TWO && sidx) ? B : A;
        const float* Wsrc = (TWO && sidx) ? W2 : W1;
        __syncthreads();   // previous contents of Asm/Wsm no longer needed
        {   // stage 64x128 A tile as 2048 float4 (coalesced 1KB per wave)
            const float4* g = (const float4*)Asrc;
#pragma unroll
            for (int it = 0; it < 8; ++it) {
                int f = t + 256 * it;       // 0..2047
                int r = f >> 5, c = f & 31; // row, float4-within-row
                int gr = rbase + r;
                float4 v = make_float4(0.f, 0.f, 0.f, 0.f);
                if (gr < nrows) v = g[(size_t)gr * 32 + c];
                *(float4*)&Asm[r * AS + 4 * c] = v;
            }
        }
#pragma unroll
        for (int ch = 0; ch < NCH; ++ch) {
            if (ch > 0) __syncthreads();
            {   // stage 128x64 W chunk as 2048 float4
                const float4* gw = (const float4*)Wsrc;
#pragma unroll
                for (int it = 0; it < 8; ++it) {
                    int f = t + 256 * it;
                    int k = f >> 4, c4 = f & 15;
                    float4 v = gw[k * (COLS / 4) + ch * 16 + c4];
                    *(float4*)&Wsm[k * 64 + 4 * c4] = v;
                }
            }
            __syncthreads();
#pragma unroll 2
            for (int k = 0; k < 128; k += 4) {
                float4 w0 = *(const float4*)&Wsm[(k + 0) * 64 + m4];
                float4 w1 = *(const float4*)&Wsm[(k + 1) * 64 + m4];
                float4 w2 = *(const float4*)&Wsm[(k + 2) * 64 + m4];
                float4 w3 = *(const float4*)&Wsm[(k + 3) * 64 + m4];
#pragma unroll
                for (int i = 0; i < 4; ++i) {
                    float4 a = *(const float4*)&Asm[(r0 + i) * AS + k];
                    fma4(acc[ch][i], a.x, w0);
                    fma4(acc[ch][i], a.y, w1);
                    fma4(acc[ch][i], a.z, w2);
                    fma4(acc[ch][i], a.w, w3);
                }
            }
        }
    }

#pragma unroll
    for (int ch = 0; ch < NCH; ++ch) {
        float4 b4 = *(const float4*)&bias[ch * 64 + m4];
#pragma unroll
        for (int i = 0; i < 4; ++i) {
            int r = rbase + r0 + i;
            if (r < nrows) {
                float4 v = acc[ch][i];
                v.x += b4.x; v.y += b4.y; v.z += b4.z; v.w += b4.w;
                if (RELU) {
                    v.x = fmaxf(v.x, 0.f); v.y = fmaxf(v.y, 0.f);
                    v.z = fmaxf(v.z, 0.f); v.w = fmaxf(v.w, 0.f);
                }
                *(float4*)&out[(size_t)r * COLS + ch * 64 + m4] = v;
            }
        }
    }
}

// ---------------------------------------------------------------------------
extern "C" void kernel_launch(void* const* d_in, const int* in_sizes, int n_in,
                              void* d_out, int out_size, void* d_ws, size_t ws_size,
                              hipStream_t stream) {
    const float* x_a   = (const float*)d_in[0];
    const float* x_b   = (const float*)d_in[1];
    const int*   ei_ab = (const int*)d_in[2];   // [2][E]: row0 src(a), row1 dst(b)
    const int*   ei_ba = (const int*)d_in[3];
    const float* Wa_in = (const float*)d_in[4];
    const float* ba_in = (const float*)d_in[5];
    const float* Wb_in = (const float*)d_in[6];
    const float* bb_in = (const float*)d_in[7];
    const float* Wl_ab = (const float*)d_in[8];   // [2][128][128]
    const float* Wr_ab = (const float*)d_in[9];
    const float* bl_ab = (const float*)d_in[10];  // [2][128]
    const float* Wl_ba = (const float*)d_in[11];
    const float* Wr_ba = (const float*)d_in[12];
    const float* bl_ba = (const float*)d_in[13];
    const float* W_out = (const float*)d_in[14];  // [128][64]
    const float* b_out = (const float*)d_in[15];
    float* out = (float*)d_out;

    // ---- workspace partition (256B aligned) ----
    char* w = (char*)d_ws;
    auto alloc = [&](size_t bytes) -> void* {
        void* pp = (void*)w;
        w += (bytes + 255) & ~(size_t)255;
        return pp;
    };
    float* hA0 = (float*)alloc((size_t)N_A * HID * 4);
    float* hA1 = (float*)alloc((size_t)N_A * HID * 4);
    float* hB0 = (float*)alloc((size_t)N_B * HID * 4);
    float* hB1 = (float*)alloc((size_t)N_B * HID * 4);
    int* indptr_b = (int*)alloc((size_t)(N_B + 1) * 4);
    int* indptr_a = (int*)alloc((size_t)(N_A + 1) * 4);
    int* col_ab   = (int*)alloc((size_t)NE * 4);
    int* col_ba   = (int*)alloc((size_t)NE * 4);
    int* deg      = (int*)alloc((size_t)N_A * 4);   // shared scratch (N_A == N_B)
    int* cursor   = (int*)alloc((size_t)N_A * 4);
    int* bsum     = (int*)alloc(256 * 4);
    int* boffs    = (int*)alloc(256 * 4);

    // ---- CSR build for both edge types ----
    auto build_csr = [&](const int* ei, int* indptr, int* col, int ndst) {
        const int* src = ei;
        const int* dst = ei + NE;
        hipMemsetAsync(deg, 0, (size_t)ndst * 4, stream);
        count_deg<<<NE / 256, 256, 0, stream>>>(dst, deg, NE);
        int nchunk = (ndst + 255) / 256;
        chunk_sum<<<nchunk, 256, 0, stream>>>(deg, bsum, ndst);
        scan_bsum<<<1, 256, 0, stream>>>(bsum, boffs, nchunk);
        scan_chunks<<<nchunk, 256, 0, stream>>>(deg, boffs, indptr, cursor, ndst, NE);
        fill_csr<<<NE / 256, 256, 0, stream>>>(src, dst, cursor, col, NE);
    };
    build_csr(ei_ab, indptr_b, col_ab, N_B);   // dst in b
    build_csr(ei_ba, indptr_a, col_ba, N_A);   // dst in a

    const int gemm_blocks_a = (N_A + 63) / 64;
    const int gemm_blocks_b = (N_B + 63) / 64;
    const int agg_blocks_a  = (N_A + 3) / 4;
    const int agg_blocks_b  = (N_B + 3) / 4;

    // ---- input projections ----
    gemm_rt<128, false, true><<<gemm_blocks_a, 256, 0, stream>>>(
        x_a, nullptr, Wa_in, nullptr, ba_in, hA0, N_A);
    gemm_rt<128, false, true><<<gemm_blocks_b, 256, 0, stream>>>(
        x_b, nullptr, Wb_in, nullptr, bb_in, hB0, N_B);

    // ---- 2 hetero layers ----
    float* ha = hA0; float* ha_alt = hA1;
    float* hb = hB0; float* hb_alt = hB1;
    for (int l = 0; l < 2; ++l) {
        const float* wl_ab = Wl_ab + (size_t)l * HID * HID;
        const float* wr_ab = Wr_ab + (size_t)l * HID * HID;
        const float* bias_ab = bl_ab + (size_t)l * HID;
        const float* wl_ba = Wl_ba + (size_t)l * HID * HID;
        const float* wr_ba = Wr_ba + (size_t)l * HID * HID;
        const float* bias_ba = bl_ba + (size_t)l * HID;

        // mean_b <- mean of h_a over edges a->b ; mean_a <- mean of h_b over b->a
        agg_mean<<<agg_blocks_b, 256, 0, stream>>>(ha, indptr_b, col_ab, hb_alt, N_B);
        agg_mean<<<agg_blocks_a, 256, 0, stream>>>(hb, indptr_a, col_ba, ha_alt, N_A);
        // h_b' = relu(mean_b@Wl_ab + bl_ab + h_b@Wr_ab)   (in-place over mean buffer)
        gemm_rt<128, true, true><<<gemm_blocks_b, 256, 0, stream>>>(
            hb_alt, hb, wl_ab, wr_ab, bias_ab, hb_alt, N_B);
        // h_a' = relu(mean_a@Wl_ba + bl_ba + h_a@Wr_ba)
        gemm_rt<128, true, true><<<gemm_blocks_a, 256, 0, stream>>>(
            ha_alt, ha, wl_ba, wr_ba, bias_ba, ha_alt, N_A);

        float* tmp;
        tmp = ha; ha = ha_alt; ha_alt = tmp;
        tmp = hb; hb = hb_alt; hb_alt = tmp;
    }

    // ---- output projection (no relu) ----
    gemm_rt<64, false, false><<<gemm_blocks_a, 256, 0, stream>>>(
        ha, nullptr, W_out, nullptr, b_out, out, N_A);
}